// Round 1
// 408.695 us; speedup vs baseline: 1.0617x; 1.0617x over previous
//
#include <hip/hip_runtime.h>
#include <hip/hip_bf16.h>

#define HN 16
#define DM 1024
#define DK 64
#define BSZ 8
#define SEQL 1024

typedef __attribute__((ext_vector_type(8))) short bf16x8;
typedef __attribute__((ext_vector_type(4))) short short4v;
typedef __attribute__((ext_vector_type(4))) float f32x4;

__device__ __forceinline__ short f2bf(float f) {
    union { float f; unsigned u; } x; x.f = f;
    unsigned u = x.u + 0x7FFFu + ((x.u >> 16) & 1u);
    return (short)(u >> 16);
}

// async global->LDS, 16B per lane. LDS dest is wave-uniform base + lane*16.
__device__ __forceinline__ void async16(const short* g, short* ldsbase) {
    __builtin_amdgcn_global_load_lds(
        (const __attribute__((address_space(1))) unsigned int*)g,
        (__attribute__((address_space(3))) unsigned int*)ldsbase, 16, 0, 0);
}

// ---------------------------------------------------------------------------
// fp32 -> bf16 cast, 8 elems/thread
// ---------------------------------------------------------------------------
__global__ __launch_bounds__(256) void cast_bf16(const float* __restrict__ in,
                                                 short* __restrict__ out) {
    size_t i = (size_t)blockIdx.x * 256 + threadIdx.x;
    float4 a = ((const float4*)in)[2 * i];
    float4 b = ((const float4*)in)[2 * i + 1];
    bf16x8 r = {f2bf(a.x), f2bf(a.y), f2bf(a.z), f2bf(a.w),
                f2bf(b.x), f2bf(b.y), f2bf(b.z), f2bf(b.w)};
    ((bf16x8*)out)[i] = r;
}

// ---------------------------------------------------------------------------
// Wt[n][k] = bf16(W[k][n])
// ---------------------------------------------------------------------------
__global__ __launch_bounds__(256) void transpose_cast(const float* __restrict__ W,
                                                      short* __restrict__ Wt) {
    __shared__ float tile[32][33];
    const int t = threadIdx.x;
    const int k0 = blockIdx.x * 32, n0 = blockIdx.y * 32;
    const int c = t & 31, r = t >> 5;
    #pragma unroll
    for (int p = 0; p < 4; ++p)
        tile[r + 8 * p][c] = W[(size_t)(k0 + r + 8 * p) * DM + n0 + c];
    __syncthreads();
    #pragma unroll
    for (int p = 0; p < 4; ++p)
        Wt[(size_t)(n0 + r + 8 * p) * DM + k0 + c] = f2bf(tile[c][r + 8 * p]);
}

// ---------------------------------------------------------------------------
// mask int32[8M] -> bits u64[128K] (1 = keep)
// ---------------------------------------------------------------------------
__global__ __launch_bounds__(256) void pack_mask(const int* __restrict__ mask,
                                                 unsigned long long* __restrict__ bits) {
    size_t i = (size_t)blockIdx.x * 256 + threadIdx.x;
    unsigned long long b = __ballot(mask[i] != 0);
    if ((threadIdx.x & 63) == 0) bits[i >> 6] = b;
}

// ---------------------------------------------------------------------------
// MFMA GEMM, 1024x1024x1024 per z. 128x128 tile, BK=32, 4 waves, 4x4 frags.
// m97 structure: linear LDS [128][32], global_load_lds width-16 staging.
// A is bf16 [s][k] (pre-cast), Wt is bf16 [n][k].
// MODE 0: C bf16 head-split [h][s][dk]   (Q/K projections)
// MODE 1: C fp32 row-major  [s][n]       (output projection)
// MODE 2: C bf16 V-transposed [h][dk][s] (V projection)
// ---------------------------------------------------------------------------
template <int MODE>
__global__ __launch_bounds__(256) void gemm_mfma(const short* __restrict__ A,
                                                 const short* __restrict__ Wt,
                                                 const float* __restrict__ bias,
                                                 void* __restrict__ Cp) {
    __shared__ __attribute__((aligned(16))) short As[128][32];
    __shared__ __attribute__((aligned(16))) short Bs[128][32];
    const int t = threadIdx.x;
    const int lane = t & 63, wv = t >> 6;
    const int wm = (wv >> 1) * 64, wn = (wv & 1) * 64;
    const int quad = lane >> 4, l15 = lane & 15;
    const int tileM = blockIdx.x * 128, tileN = blockIdx.y * 128;
    const size_t zoff = (size_t)blockIdx.z * DM * SEQL;
    const short* Az = A + zoff;

    // staging geometry: issue p covers rows [p*64, p*64+64); wave wv covers
    // 16 rows within it; lane l -> row +(l>>2), col elems (l&3)*8.
    const int sr = wv * 16 + (lane >> 2);
    const int sc = (lane & 3) * 8;

    f32x4 acc[4][4];
    #pragma unroll
    for (int i = 0; i < 4; ++i)
        #pragma unroll
        for (int j = 0; j < 4; ++j) acc[i][j] = {0.f, 0.f, 0.f, 0.f};

    for (int k0 = 0; k0 < DM; k0 += 32) {
        #pragma unroll
        for (int p = 0; p < 2; ++p) {
            async16(Az + (size_t)(tileM + p * 64 + sr) * DM + k0 + sc,
                    &As[p * 64 + wv * 16][0]);
            async16(Wt + (size_t)(tileN + p * 64 + sr) * DM + k0 + sc,
                    &Bs[p * 64 + wv * 16][0]);
        }
        __syncthreads();  // drains vmcnt(0) before barrier
        bf16x8 a[4], b[4];
        #pragma unroll
        for (int i = 0; i < 4; ++i) a[i] = *(const bf16x8*)&As[wm + i * 16 + l15][quad * 8];
        #pragma unroll
        for (int j = 0; j < 4; ++j) b[j] = *(const bf16x8*)&Bs[wn + j * 16 + l15][quad * 8];
        #pragma unroll
        for (int i = 0; i < 4; ++i)
            #pragma unroll
            for (int j = 0; j < 4; ++j)
                acc[i][j] = __builtin_amdgcn_mfma_f32_16x16x32_bf16(a[i], b[j], acc[i][j], 0, 0, 0);
        __syncthreads();
    }

    #pragma unroll
    for (int i = 0; i < 4; ++i)
        #pragma unroll
        for (int j = 0; j < 4; ++j)
            #pragma unroll
            for (int rr = 0; rr < 4; ++rr) {
                int row = tileM + wm + i * 16 + quad * 4 + rr;
                int col = tileN + wn + j * 16 + l15;
                float v = acc[i][j][rr] + bias[col];
                if (MODE == 0) {
                    short* C = (short*)Cp + zoff;
                    C[((size_t)(col >> 6) * SEQL + row) * DK + (col & 63)] = f2bf(v);
                } else if (MODE == 1) {
                    float* C = (float*)Cp + zoff;
                    C[(size_t)row * DM + col] = v;
                } else {
                    short* C = (short*)Cp + zoff;
                    C[(size_t)col * SEQL + row] = f2bf(v);  // [h][dk][s]
                }
            }
}

// ---------------------------------------------------------------------------
// MFMA attention. Block = (qtile 64, h, z). Q/K head-split [h][s][dk];
// V pre-transposed [h][dk][s]. Unnormalized softmax (masked p=0), /L at end.
// ---------------------------------------------------------------------------
template <bool USE_BITS>
__global__ __launch_bounds__(256) void attn_mfma(const short* __restrict__ Qw,
                                                 const short* __restrict__ Kw,
                                                 const short* __restrict__ Vt,
                                                 const void* __restrict__ maskp,
                                                 short* __restrict__ ctx) {
    __shared__ __attribute__((aligned(16))) short Qs[64][72];
    __shared__ __attribute__((aligned(16))) short Ks[64][72];
    __shared__ __attribute__((aligned(16))) short Vs[64][72];     // [d][j]
    __shared__ __attribute__((aligned(16))) short Ps[4][16][72];  // per-wave
    const int t = threadIdx.x;
    const int lane = t & 63, w = t >> 6;
    const int quad = lane >> 4, l15 = lane & 15;
    const int q0 = blockIdx.x * 64;
    const int h = blockIdx.y;
    const size_t zoff = (size_t)blockIdx.z * DM * SEQL;
    const short* Qb = Qw + zoff + (size_t)h * SEQL * DK;
    const short* Kb = Kw + zoff + (size_t)h * SEQL * DK;
    const short* Vb = Vt + zoff + (size_t)h * DK * SEQL;

    #pragma unroll
    for (int p = 0; p < 2; ++p) {
        int cc = t + 256 * p;
        int row = cc >> 3, off = (cc & 7) * 8;
        *(bf16x8*)&Qs[row][off] = *(const bf16x8*)(Qb + (size_t)(q0 + row) * DK + off);
    }

    f32x4 o[4];
    #pragma unroll
    for (int td = 0; td < 4; ++td) o[td] = {0.f, 0.f, 0.f, 0.f};
    float Lacc[4] = {0.f, 0.f, 0.f, 0.f};

    for (int j0 = 0; j0 < SEQL; j0 += 64) {
        #pragma unroll
        for (int p = 0; p < 2; ++p) {
            int cc = t + 256 * p;
            int row = cc >> 3, off = (cc & 7) * 8;
            *(bf16x8*)&Ks[row][off] = *(const bf16x8*)(Kb + (size_t)(j0 + row) * DK + off);
            *(bf16x8*)&Vs[row][off] = *(const bf16x8*)(Vb + (size_t)row * SEQL + j0 + off);
        }
        __syncthreads();

        unsigned long long mw[4];
        if (USE_BITS) {
            const unsigned long long* mb =
                (const unsigned long long*)maskp + (size_t)blockIdx.z * SEQL * 16;
            #pragma unroll
            for (int rr = 0; rr < 4; ++rr)
                mw[rr] = mb[(size_t)(q0 + w * 16 + quad * 4 + rr) * 16 + (j0 >> 6)];
        }

        #pragma unroll
        for (int tn = 0; tn < 4; ++tn) {
            f32x4 s = {0.f, 0.f, 0.f, 0.f};
            #pragma unroll
            for (int ks = 0; ks < 2; ++ks) {
                bf16x8 aq = *(const bf16x8*)&Qs[w * 16 + l15][ks * 32 + quad * 8];
                bf16x8 bk = *(const bf16x8*)&Ks[tn * 16 + l15][ks * 32 + quad * 8];
                s = __builtin_amdgcn_mfma_f32_16x16x32_bf16(aq, bk, s, 0, 0, 0);
            }
            #pragma unroll
            for (int rr = 0; rr < 4; ++rr) {
                bool keep;
                if (USE_BITS) {
                    keep = (mw[rr] >> (tn * 16 + l15)) & 1ull;
                } else {
                    const int* mb = (const int*)maskp + (size_t)blockIdx.z * SEQL * SEQL;
                    keep = mb[(size_t)(q0 + w * 16 + quad * 4 + rr) * SEQL + j0 + tn * 16 + l15] != 0;
                }
                float p = keep ? __expf(s[rr] * 0.125f) : 0.0f;
                Lacc[rr] += p;
                Ps[w][quad * 4 + rr][tn * 16 + l15] = f2bf(p);
            }
        }
        // Ps is wave-private: no barrier needed before reading it back.
        #pragma unroll
        for (int td = 0; td < 4; ++td)
            #pragma unroll
            for (int ks = 0; ks < 2; ++ks) {
                bf16x8 ap = *(const bf16x8*)&Ps[w][l15][ks * 32 + quad * 8];
                bf16x8 bv = *(const bf16x8*)&Vs[td * 16 + l15][ks * 32 + quad * 8];
                o[td] = __builtin_amdgcn_mfma_f32_16x16x32_bf16(ap, bv, o[td], 0, 0, 0);
            }
        __syncthreads();  // all reads of Ks/Vs done before restage
    }

    #pragma unroll
    for (int rr = 0; rr < 4; ++rr) {
        float l = Lacc[rr];
        l += __shfl_xor(l, 1);
        l += __shfl_xor(l, 2);
        l += __shfl_xor(l, 4);
        l += __shfl_xor(l, 8);
        Lacc[rr] = 1.0f / l;
    }
    short* cb = ctx + zoff;
    #pragma unroll
    for (int td = 0; td < 4; ++td)
        #pragma unroll
        for (int rr = 0; rr < 4; ++rr) {
            int rq = q0 + w * 16 + quad * 4 + rr;
            int cd = h * 64 + td * 16 + l15;
            cb[(size_t)rq * DM + cd] = f2bf(o[td][rr] * Lacc[rr]);
        }
}

extern "C" void kernel_launch(void* const* d_in, const int* in_sizes, int n_in,
                              void* d_out, int out_size, void* d_ws, size_t ws_size,
                              hipStream_t stream) {
    const float* q  = (const float*)d_in[0];
    const float* k  = (const float*)d_in[1];
    const float* v  = (const float*)d_in[2];
    const int* mask = (const int*)d_in[3];
    const float* Wq = (const float*)d_in[4];
    const float* bq = (const float*)d_in[5];
    const float* Wk = (const float*)d_in[6];
    const float* bk = (const float*)d_in[7];
    const float* Wv = (const float*)d_in[8];
    const float* bv = (const float*)d_in[9];
    const float* Wo = (const float*)d_in[10];
    const float* bo = (const float*)d_in[11];
    float* out = (float*)d_out;

    const size_t MB = (size_t)1 << 20;
    const size_t MEL = (size_t)1024 * 1024;
    char* base = (char*)d_ws;

    short* Wqt = (short*)(base + 0 * 2 * MB);
    short* Wkt = (short*)(base + 1 * 2 * MB);
    short* Wvt = (short*)(base + 2 * 2 * MB);
    short* Wot = (short*)(base + 3 * 2 * MB);

    // tiers: weights 8MB [+ bits 1MB] + 4 bufs * z * 2MB
    int zdim;
    bool use_bits;
    if      (ws_size >= 74 * MB) { zdim = 8; use_bits = true; }
    else if (ws_size >= 42 * MB) { zdim = 4; use_bits = true; }
    else if (ws_size >= 26 * MB) { zdim = 2; use_bits = true; }
    else if (ws_size >= 18 * MB) { zdim = 1; use_bits = true; }
    else                         { zdim = 1; use_bits = false; }

    unsigned long long* bits = (unsigned long long*)(base + 8 * MB);
    char* bufs = base + (use_bits ? 9 : 8) * MB;
    const size_t bufB = (size_t)zdim * 2 * MB;
    short* Qw  = (short*)(bufs);
    short* Kw  = (short*)(bufs + bufB);
    short* Vw  = (short*)(bufs + 2 * bufB);
    short* ctx = (short*)(bufs + 3 * bufB);

    transpose_cast<<<dim3(32, 32), 256, 0, stream>>>(Wq, Wqt);
    transpose_cast<<<dim3(32, 32), 256, 0, stream>>>(Wk, Wkt);
    transpose_cast<<<dim3(32, 32), 256, 0, stream>>>(Wv, Wvt);
    transpose_cast<<<dim3(32, 32), 256, 0, stream>>>(Wo, Wot);
    if (use_bits)
        pack_mask<<<(BSZ * SEQL * SEQL) / 256, 256, 0, stream>>>(mask, bits);

    const int iters = BSZ / zdim;
    for (int it = 0; it < iters; ++it) {
        const size_t boff = (size_t)it * zdim * MEL;
        const float* qb = q + boff;
        const float* kb = k + boff;
        const float* vb = v + boff;
        float* ob = out + boff;
        const void* mb = use_bits
            ? (const void*)(bits + (size_t)it * zdim * SEQL * 16)
            : (const void*)(mask + (size_t)it * zdim * SEQL * SEQL);

        const int castGrid = zdim * 512;  // zdim*1M elems / 8 per thread / 256
        // ctx is dead until attn writes it: reuse as bf16 A-scratch.
        cast_bf16<<<castGrid, 256, 0, stream>>>(qb, ctx);
        gemm_mfma<0><<<dim3(8, 8, zdim), 256, 0, stream>>>(ctx, Wqt, bq, Qw);
        cast_bf16<<<castGrid, 256, 0, stream>>>(kb, ctx);
        gemm_mfma<0><<<dim3(8, 8, zdim), 256, 0, stream>>>(ctx, Wkt, bk, Kw);
        cast_bf16<<<castGrid, 256, 0, stream>>>(vb, ctx);
        gemm_mfma<2><<<dim3(8, 8, zdim), 256, 0, stream>>>(ctx, Wvt, bv, Vw);

        if (use_bits)
            attn_mfma<true><<<dim3(16, 16, zdim), 256, 0, stream>>>(Qw, Kw, Vw, mb, ctx);
        else
            attn_mfma<false><<<dim3(16, 16, zdim), 256, 0, stream>>>(Qw, Kw, Vw, mb, ctx);

        gemm_mfma<1><<<dim3(8, 8, zdim), 256, 0, stream>>>(ctx, Wot, bo, ob);
    }
}

// Round 2
// 395.986 us; speedup vs baseline: 1.0958x; 1.0321x over previous
//
#include <hip/hip_runtime.h>
#include <hip/hip_bf16.h>

#define HN 16
#define DM 1024
#define DK 64
#define BSZ 8
#define SEQL 1024

typedef __attribute__((ext_vector_type(8))) short bf16x8;
typedef __attribute__((ext_vector_type(4))) short short4v;
typedef __attribute__((ext_vector_type(4))) float f32x4;

__device__ __forceinline__ short f2bf(float f) {
    union { float f; unsigned u; } x; x.f = f;
    unsigned u = x.u + 0x7FFFu + ((x.u >> 16) & 1u);
    return (short)(u >> 16);
}

// async global->LDS, 16B per lane. LDS dest is wave-uniform base + lane*16.
__device__ __forceinline__ void async16(const short* g, short* ldsbase) {
    __builtin_amdgcn_global_load_lds(
        (const __attribute__((address_space(1))) unsigned int*)g,
        (__attribute__((address_space(3))) unsigned int*)ldsbase, 16, 0, 0);
}

// pack 4 f32 -> 4 bf16 (RNE) via v_cvt_pk_bf16_f32
__device__ __forceinline__ short4v pack4bf(float v0, float v1, float v2, float v3) {
    unsigned pk0, pk1;
    asm("v_cvt_pk_bf16_f32 %0, %1, %2" : "=v"(pk0) : "v"(v0), "v"(v1));
    asm("v_cvt_pk_bf16_f32 %0, %1, %2" : "=v"(pk1) : "v"(v2), "v"(v3));
    union { unsigned u[2]; short4v s4; } u_;
    u_.u[0] = pk0; u_.u[1] = pk1;
    return u_.s4;
}

// ---------------------------------------------------------------------------
// fp32 -> bf16 cast, 8 elems/thread
// ---------------------------------------------------------------------------
__global__ __launch_bounds__(256) void cast_bf16(const float* __restrict__ in,
                                                 short* __restrict__ out) {
    size_t i = (size_t)blockIdx.x * 256 + threadIdx.x;
    float4 a = ((const float4*)in)[2 * i];
    float4 b = ((const float4*)in)[2 * i + 1];
    bf16x8 r = {f2bf(a.x), f2bf(a.y), f2bf(a.z), f2bf(a.w),
                f2bf(b.x), f2bf(b.y), f2bf(b.z), f2bf(b.w)};
    ((bf16x8*)out)[i] = r;
}

// ---------------------------------------------------------------------------
// Wt[n][k] = bf16(W[k][n])
// ---------------------------------------------------------------------------
__global__ __launch_bounds__(256) void transpose_cast(const float* __restrict__ W,
                                                      short* __restrict__ Wt) {
    __shared__ float tile[32][33];
    const int t = threadIdx.x;
    const int k0 = blockIdx.x * 32, n0 = blockIdx.y * 32;
    const int c = t & 31, r = t >> 5;
    #pragma unroll
    for (int p = 0; p < 4; ++p)
        tile[r + 8 * p][c] = W[(size_t)(k0 + r + 8 * p) * DM + n0 + c];
    __syncthreads();
    #pragma unroll
    for (int p = 0; p < 4; ++p)
        Wt[(size_t)(n0 + r + 8 * p) * DM + k0 + c] = f2bf(tile[c][r + 8 * p]);
}

// ---------------------------------------------------------------------------
// mask int32[8M] -> bits u64[128K] (1 = keep)
// ---------------------------------------------------------------------------
__global__ __launch_bounds__(256) void pack_mask(const int* __restrict__ mask,
                                                 unsigned long long* __restrict__ bits) {
    size_t i = (size_t)blockIdx.x * 256 + threadIdx.x;
    unsigned long long b = __ballot(mask[i] != 0);
    if ((threadIdx.x & 63) == 0) bits[i >> 6] = b;
}

// ---------------------------------------------------------------------------
// MFMA GEMM, 1024x1024x1024 per z. 128x128 tile, BK=32, 4 waves, 4x4 frags.
// m97 structure: linear LDS [128][32], global_load_lds width-16 staging.
// A is bf16 [s][k] (pre-cast), Wt is bf16 [n][k].
// MODE 0: C bf16 head-split [h][s][dk]   (Q/K projections)
// MODE 1: C fp32 row-major  [s][n]       (output projection)
// MODE 2: C bf16 V-transposed [h][dk][s] (V projection), packed 8B stores
// ---------------------------------------------------------------------------
template <int MODE>
__global__ __launch_bounds__(256) void gemm_mfma(const short* __restrict__ A,
                                                 const short* __restrict__ Wt,
                                                 const float* __restrict__ bias,
                                                 void* __restrict__ Cp) {
    __shared__ __attribute__((aligned(16))) short As[128][32];
    __shared__ __attribute__((aligned(16))) short Bs[128][32];
    const int t = threadIdx.x;
    const int lane = t & 63, wv = t >> 6;
    const int wm = (wv >> 1) * 64, wn = (wv & 1) * 64;
    const int quad = lane >> 4, l15 = lane & 15;
    const int tileM = blockIdx.x * 128, tileN = blockIdx.y * 128;
    const size_t zoff = (size_t)blockIdx.z * DM * SEQL;
    const short* Az = A + zoff;

    const int sr = wv * 16 + (lane >> 2);
    const int sc = (lane & 3) * 8;

    f32x4 acc[4][4];
    #pragma unroll
    for (int i = 0; i < 4; ++i)
        #pragma unroll
        for (int j = 0; j < 4; ++j) acc[i][j] = {0.f, 0.f, 0.f, 0.f};

    for (int k0 = 0; k0 < DM; k0 += 32) {
        #pragma unroll
        for (int p = 0; p < 2; ++p) {
            async16(Az + (size_t)(tileM + p * 64 + sr) * DM + k0 + sc,
                    &As[p * 64 + wv * 16][0]);
            async16(Wt + (size_t)(tileN + p * 64 + sr) * DM + k0 + sc,
                    &Bs[p * 64 + wv * 16][0]);
        }
        __syncthreads();  // drains vmcnt(0) before barrier
        bf16x8 a[4], b[4];
        #pragma unroll
        for (int i = 0; i < 4; ++i) a[i] = *(const bf16x8*)&As[wm + i * 16 + l15][quad * 8];
        #pragma unroll
        for (int j = 0; j < 4; ++j) b[j] = *(const bf16x8*)&Bs[wn + j * 16 + l15][quad * 8];
        #pragma unroll
        for (int i = 0; i < 4; ++i)
            #pragma unroll
            for (int j = 0; j < 4; ++j)
                acc[i][j] = __builtin_amdgcn_mfma_f32_16x16x32_bf16(a[i], b[j], acc[i][j], 0, 0, 0);
        __syncthreads();
    }

    if (MODE == 2) {
        // rr = consecutive output rows at fixed col -> one 8B store per (i,j)
        short* C = (short*)Cp + zoff;
        #pragma unroll
        for (int i = 0; i < 4; ++i)
            #pragma unroll
            for (int j = 0; j < 4; ++j) {
                int rowb = tileM + wm + i * 16 + quad * 4;
                int col = tileN + wn + j * 16 + l15;
                float b = bias[col];
                short4v s4 = pack4bf(acc[i][j][0] + b, acc[i][j][1] + b,
                                     acc[i][j][2] + b, acc[i][j][3] + b);
                *(short4v*)(C + (size_t)col * SEQL + rowb) = s4;  // [h][dk][s]
            }
    } else {
        #pragma unroll
        for (int i = 0; i < 4; ++i)
            #pragma unroll
            for (int j = 0; j < 4; ++j)
                #pragma unroll
                for (int rr = 0; rr < 4; ++rr) {
                    int row = tileM + wm + i * 16 + quad * 4 + rr;
                    int col = tileN + wn + j * 16 + l15;
                    float v = acc[i][j][rr] + bias[col];
                    if (MODE == 0) {
                        short* C = (short*)Cp + zoff;
                        C[((size_t)(col >> 6) * SEQL + row) * DK + (col & 63)] = f2bf(v);
                    } else {
                        float* C = (float*)Cp + zoff;
                        C[(size_t)row * DM + col] = v;
                    }
                }
    }
}

// ---------------------------------------------------------------------------
// MFMA attention, swapped-QK^T softmax (T12-lite).
// 1D grid (XCD-swizzled): vb -> (qtile, h, z). Q/K head-split [h][s][dk];
// V pre-transposed [h][dk][s]. Unnormalized softmax (masked p=0), /L at end.
// Swapped QK^T: s = mfma(K,Q) gives lane (quad,l15) the scores for
// q = w*16+l15, j = tn*16+quad*4+{0..3} -> j-contiguous in-lane: packed
// cvt_pk + single ds_write_b64, and ONE mask u64 per lane per j-tile.
// ---------------------------------------------------------------------------
template <bool USE_BITS>
__global__ __launch_bounds__(256) void attn_mfma(const short* __restrict__ Qw,
                                                 const short* __restrict__ Kw,
                                                 const short* __restrict__ Vt,
                                                 const void* __restrict__ maskp,
                                                 short* __restrict__ ctx) {
    __shared__ __attribute__((aligned(16))) short Qs[64][72];
    __shared__ __attribute__((aligned(16))) short Ks[64][72];
    __shared__ __attribute__((aligned(16))) short Vs[64][72];     // [d][j]
    __shared__ __attribute__((aligned(16))) short Ps[4][16][72];  // per-wave [q][j]
    const int t = threadIdx.x;
    const int lane = t & 63, w = t >> 6;
    const int quad = lane >> 4, l15 = lane & 15;
    // XCD swizzle: 16 consecutive q-tiles (sharing K/V) land on one XCD's L2
    const int nwg = gridDim.x;            // 256*zdim, % 8 == 0
    const int cpx = nwg >> 3;
    const int vb = (blockIdx.x & 7) * cpx + (blockIdx.x >> 3);
    const int q0 = (vb & 15) * 64;
    const int h = (vb >> 4) & 15;
    const int z = vb >> 8;
    const size_t zoff = (size_t)z * DM * SEQL;
    const short* Qb = Qw + zoff + (size_t)h * SEQL * DK;
    const short* Kb = Kw + zoff + (size_t)h * SEQL * DK;
    const short* Vb = Vt + zoff + (size_t)h * DK * SEQL;

    #pragma unroll
    for (int p = 0; p < 2; ++p) {
        int cc = t + 256 * p;
        int row = cc >> 3, off = (cc & 7) * 8;
        *(bf16x8*)&Qs[row][off] = *(const bf16x8*)(Qb + (size_t)(q0 + row) * DK + off);
    }

    f32x4 o[4];
    #pragma unroll
    for (int td = 0; td < 4; ++td) o[td] = {0.f, 0.f, 0.f, 0.f};
    float Lacc = 0.f;  // partial row-sum for q = w*16+l15 over this lane's j's

    for (int j0 = 0; j0 < SEQL; j0 += 64) {
        #pragma unroll
        for (int p = 0; p < 2; ++p) {
            int cc = t + 256 * p;
            int row = cc >> 3, off = (cc & 7) * 8;
            *(bf16x8*)&Ks[row][off] = *(const bf16x8*)(Kb + (size_t)(j0 + row) * DK + off);
            *(bf16x8*)&Vs[row][off] = *(const bf16x8*)(Vb + (size_t)row * SEQL + j0 + off);
        }
        __syncthreads();

        unsigned long long mw = 0;
        if (USE_BITS) {
            const unsigned long long* mb =
                (const unsigned long long*)maskp + (size_t)z * SEQL * 16;
            mw = mb[(size_t)(q0 + w * 16 + l15) * 16 + (j0 >> 6)];
        }

        #pragma unroll
        for (int tn = 0; tn < 4; ++tn) {
            f32x4 s = {0.f, 0.f, 0.f, 0.f};
            #pragma unroll
            for (int ks = 0; ks < 2; ++ks) {
                bf16x8 ak = *(const bf16x8*)&Ks[tn * 16 + l15][ks * 32 + quad * 8];
                bf16x8 bq = *(const bf16x8*)&Qs[w * 16 + l15][ks * 32 + quad * 8];
                s = __builtin_amdgcn_mfma_f32_16x16x32_bf16(ak, bq, s, 0, 0, 0);
            }
            // s[rr] = S[q = w*16+l15][j = j0 + tn*16 + quad*4 + rr]
            float pv[4];
            #pragma unroll
            for (int rr = 0; rr < 4; ++rr) {
                bool keep;
                if (USE_BITS) {
                    keep = (mw >> (tn * 16 + quad * 4 + rr)) & 1ull;
                } else {
                    const int* mi = (const int*)maskp + (size_t)z * SEQL * SEQL;
                    keep = mi[(size_t)(q0 + w * 16 + l15) * SEQL + j0 + tn * 16 + quad * 4 + rr] != 0;
                }
                float e = __expf(s[rr] * 0.125f);
                pv[rr] = keep ? e : 0.0f;
                Lacc += pv[rr];
            }
            *(short4v*)&Ps[w][l15][tn * 16 + quad * 4] =
                pack4bf(pv[0], pv[1], pv[2], pv[3]);
        }
        // Ps is wave-private: no barrier needed before reading it back.
        #pragma unroll
        for (int td = 0; td < 4; ++td)
            #pragma unroll
            for (int ks = 0; ks < 2; ++ks) {
                bf16x8 ap = *(const bf16x8*)&Ps[w][l15][ks * 32 + quad * 8];
                bf16x8 bv = *(const bf16x8*)&Vs[td * 16 + l15][ks * 32 + quad * 8];
                o[td] = __builtin_amdgcn_mfma_f32_16x16x32_bf16(ap, bv, o[td], 0, 0, 0);
            }
        __syncthreads();  // all reads of Ks/Vs done before restage
    }

    // full row-sum: lanes sharing l15 (4 quads) hold disjoint j-partials
    Lacc += __shfl_xor(Lacc, 16);
    Lacc += __shfl_xor(Lacc, 32);
    float Linv = 1.0f / Lacc;  // valid for q = w*16+l15, all quads
    float Linv4[4];
    #pragma unroll
    for (int rr = 0; rr < 4; ++rr)
        Linv4[rr] = __shfl(Linv, quad * 4 + rr);  // lanes 0..15 hold q=l15

    short* cb = ctx + zoff;
    #pragma unroll
    for (int td = 0; td < 4; ++td)
        #pragma unroll
        for (int rr = 0; rr < 4; ++rr) {
            int rq = q0 + w * 16 + quad * 4 + rr;
            int cd = h * 64 + td * 16 + l15;
            cb[(size_t)rq * DM + cd] = f2bf(o[td][rr] * Linv4[rr]);
        }
}

extern "C" void kernel_launch(void* const* d_in, const int* in_sizes, int n_in,
                              void* d_out, int out_size, void* d_ws, size_t ws_size,
                              hipStream_t stream) {
    const float* q  = (const float*)d_in[0];
    const float* k  = (const float*)d_in[1];
    const float* v  = (const float*)d_in[2];
    const int* mask = (const int*)d_in[3];
    const float* Wq = (const float*)d_in[4];
    const float* bq = (const float*)d_in[5];
    const float* Wk = (const float*)d_in[6];
    const float* bk = (const float*)d_in[7];
    const float* Wv = (const float*)d_in[8];
    const float* bv = (const float*)d_in[9];
    const float* Wo = (const float*)d_in[10];
    const float* bo = (const float*)d_in[11];
    float* out = (float*)d_out;

    const size_t MB = (size_t)1 << 20;
    const size_t MEL = (size_t)1024 * 1024;
    char* base = (char*)d_ws;

    short* Wqt = (short*)(base + 0 * 2 * MB);
    short* Wkt = (short*)(base + 1 * 2 * MB);
    short* Wvt = (short*)(base + 2 * 2 * MB);
    short* Wot = (short*)(base + 3 * 2 * MB);

    // tiers: weights 8MB [+ bits 1MB] + 4 bufs * z * 2MB
    int zdim;
    bool use_bits;
    if      (ws_size >= 74 * MB) { zdim = 8; use_bits = true; }
    else if (ws_size >= 42 * MB) { zdim = 4; use_bits = true; }
    else if (ws_size >= 26 * MB) { zdim = 2; use_bits = true; }
    else if (ws_size >= 18 * MB) { zdim = 1; use_bits = true; }
    else                         { zdim = 1; use_bits = false; }

    unsigned long long* bits = (unsigned long long*)(base + 8 * MB);
    char* bufs = base + (use_bits ? 9 : 8) * MB;
    const size_t bufB = (size_t)zdim * 2 * MB;
    short* Qw  = (short*)(bufs);
    short* Kw  = (short*)(bufs + bufB);
    short* Vw  = (short*)(bufs + 2 * bufB);
    short* ctx = (short*)(bufs + 3 * bufB);

    transpose_cast<<<dim3(32, 32), 256, 0, stream>>>(Wq, Wqt);
    transpose_cast<<<dim3(32, 32), 256, 0, stream>>>(Wk, Wkt);
    transpose_cast<<<dim3(32, 32), 256, 0, stream>>>(Wv, Wvt);
    transpose_cast<<<dim3(32, 32), 256, 0, stream>>>(Wo, Wot);
    if (use_bits)
        pack_mask<<<(BSZ * SEQL * SEQL) / 256, 256, 0, stream>>>(mask, bits);

    const int iters = BSZ / zdim;
    for (int it = 0; it < iters; ++it) {
        const size_t boff = (size_t)it * zdim * MEL;
        const float* qb = q + boff;
        const float* kb = k + boff;
        const float* vb = v + boff;
        float* ob = out + boff;
        const void* mb = use_bits
            ? (const void*)(bits + (size_t)it * zdim * SEQL * 16)
            : (const void*)(mask + (size_t)it * zdim * SEQL * SEQL);

        const int castGrid = zdim * 512;  // zdim*1M elems / 8 per thread / 256
        // ctx is dead until attn writes it: reuse as bf16 A-scratch.
        cast_bf16<<<castGrid, 256, 0, stream>>>(qb, ctx);
        gemm_mfma<0><<<dim3(8, 8, zdim), 256, 0, stream>>>(ctx, Wqt, bq, Qw);
        cast_bf16<<<castGrid, 256, 0, stream>>>(kb, ctx);
        gemm_mfma<0><<<dim3(8, 8, zdim), 256, 0, stream>>>(ctx, Wkt, bk, Kw);
        cast_bf16<<<castGrid, 256, 0, stream>>>(vb, ctx);
        gemm_mfma<2><<<dim3(8, 8, zdim), 256, 0, stream>>>(ctx, Wvt, bv, Vw);

        const int attnBlocks = 16 * 16 * zdim;  // 1D, XCD-swizzled in-kernel
        if (use_bits)
            attn_mfma<true><<<attnBlocks, 256, 0, stream>>>(Qw, Kw, Vw, mb, ctx);
        else
            attn_mfma<false><<<attnBlocks, 256, 0, stream>>>(Qw, Kw, Vw, mb, ctx);

        gemm_mfma<1><<<dim3(8, 8, zdim), 256, 0, stream>>>(ctx, Wot, bo, ob);
    }
}